// Round 10
// baseline (367.942 us; speedup 1.0000x reference)
//
#include <hip/hip_runtime.h>

#define NN 100000
#define NE 800000
#define DD 16
#define ALPHA 0.1f

typedef __attribute__((ext_vector_type(2))) float f32x2;

// packed fp32: d = {x,x} * w + d   (all VOP3P f32 operands must be VGPR pairs)
__device__ __forceinline__ void pk_fma(f32x2 &d, float x, f32x2 w) {
  f32x2 xx; xx.x = x; xx.y = x;
  asm("v_pk_fma_f32 %0, %1, %2, %0" : "+v"(d) : "v"(xx), "v"(w));
}
__device__ __forceinline__ void pk_add(f32x2 &d, f32x2 s) {
  asm("v_pk_add_f32 %0, %1, %0" : "+v"(d) : "v"(s));
}

__device__ __forceinline__ void load16(const float* __restrict__ p, float* r) {
  float4 v0 = *(const float4*)(p + 0);
  float4 v1 = *(const float4*)(p + 4);
  float4 v2 = *(const float4*)(p + 8);
  float4 v3 = *(const float4*)(p + 12);
  r[0]=v0.x; r[1]=v0.y; r[2]=v0.z; r[3]=v0.w;
  r[4]=v1.x; r[5]=v1.y; r[6]=v1.z; r[7]=v1.w;
  r[8]=v2.x; r[9]=v2.y; r[10]=v2.z; r[11]=v2.w;
  r[12]=v3.x; r[13]=v3.y; r[14]=v3.z; r[15]=v3.w;
}

__device__ __forceinline__ void store16(float* __restrict__ p, const float* r) {
  *(float4*)(p + 0)  = make_float4(r[0], r[1], r[2], r[3]);
  *(float4*)(p + 4)  = make_float4(r[4], r[5], r[6], r[7]);
  *(float4*)(p + 8)  = make_float4(r[8], r[9], r[10], r[11]);
  *(float4*)(p + 12) = make_float4(r[12], r[13], r[14], r[15]);
}

__device__ __forceinline__ unsigned f2bf(float x) {  // RNE f32 -> bf16 bits
  unsigned b = __float_as_uint(x);
  return (b + 0x7FFFu + ((b >> 16) & 1u)) >> 16;
}

// ---------------------------------------------------------------------------
// hist + rank over unified [in | out] histogram of length 2N
// ---------------------------------------------------------------------------
__global__ __launch_bounds__(256) void hist_kernel(
    const int* __restrict__ ei, int* __restrict__ hist,
    int* __restrict__ rank_dst, int* __restrict__ rank_src)
{
  int e = blockIdx.x * 256 + threadIdx.x;
  if (e >= NE) return;
  int s = ei[e];
  int d = ei[NE + e];
  rank_dst[e] = atomicAdd(&hist[d], 1);
  rank_src[e] = atomicAdd(&hist[NN + s], 1);
}

__global__ __launch_bounds__(256) void scan1_kernel(
    const int* __restrict__ in, int* __restrict__ out, int* __restrict__ sums, int L)
{
  __shared__ int sh[256];
  int t = threadIdx.x;
  int i0 = blockIdx.x * 1024 + t * 4;
  int v0 = (i0 + 0 < L) ? in[i0 + 0] : 0;
  int v1 = (i0 + 1 < L) ? in[i0 + 1] : 0;
  int v2 = (i0 + 2 < L) ? in[i0 + 2] : 0;
  int v3 = (i0 + 3 < L) ? in[i0 + 3] : 0;
  int tot = v0 + v1 + v2 + v3;
  sh[t] = tot;
  __syncthreads();
  int val = tot;
  for (int off = 1; off < 256; off <<= 1) {
    int x = (t >= off) ? sh[t - off] : 0;
    __syncthreads();
    val += x; sh[t] = val;
    __syncthreads();
  }
  if (t == 255) sums[blockIdx.x] = val;
  int run = val - tot;
  if (i0 + 0 < L) out[i0 + 0] = run; run += v0;
  if (i0 + 1 < L) out[i0 + 1] = run; run += v1;
  if (i0 + 2 < L) out[i0 + 2] = run; run += v2;
  if (i0 + 3 < L) out[i0 + 3] = run;
}

__global__ __launch_bounds__(256) void scan2_kernel(
    int* __restrict__ sums, int nb, int* __restrict__ out_total)
{
  __shared__ int sh[256];
  int t = threadIdx.x;
  int v = (t < nb) ? sums[t] : 0;
  sh[t] = v;
  __syncthreads();
  int val = v;
  for (int off = 1; off < 256; off <<= 1) {
    int x = (t >= off) ? sh[t - off] : 0;
    __syncthreads();
    val += x; sh[t] = val;
    __syncthreads();
  }
  if (t < nb) sums[t] = val - v;
  if (t == 255) *out_total = val;   // sentinel = 2*NE at base[2N]
}

__global__ __launch_bounds__(256) void scan3_kernel(
    int* __restrict__ out, const int* __restrict__ sums, int L)
{
  int i = blockIdx.x * 256 + threadIdx.x;
  if (i < L) out[i] += sums[i >> 10];
}

// atomic-free payload scatter into unified pay[2*NE]
__global__ __launch_bounds__(256) void scatter_kernel(
    const int* __restrict__ ei, const float* __restrict__ ea, const float* __restrict__ a,
    const int* __restrict__ base,
    const int* __restrict__ rank_dst, const int* __restrict__ rank_src,
    float4* __restrict__ pay, float2* __restrict__ pay_au)
{
  int e = blockIdx.x * 256 + threadIdx.x;
  if (e >= NE) return;
  int s = ei[e];
  int d = ei[NE + e];
  float e0 = ea[3 * (size_t)e], e1 = ea[3 * (size_t)e + 1], e2 = ea[3 * (size_t)e + 2];
  int sl = (s == d);
  int pd = base[d] + rank_dst[e];
  pay[pd] = make_float4(__int_as_float(sl ? -1 : s), e0, e1, e2);
  int ps = base[NN + s] + rank_src[e];
  pay[ps] = make_float4(__int_as_float(sl ? -1 : d), e0, e1, e2);
  pay_au[ps - NE] = make_float2(__int_as_float(d), a[e]);
}

// ---------------------------------------------------------------------------
// Degree-bucket permutation of the 2N (node,dir) groups (64 buckets).
// ---------------------------------------------------------------------------
__global__ __launch_bounds__(256) void dbucket_kernel(
    const int* __restrict__ base, int* __restrict__ dhist)
{
  __shared__ int lh[64];
  int t = threadIdx.x;
  if (t < 64) lh[t] = 0;
  __syncthreads();
  int g = blockIdx.x * 256 + t;
  if (g < 2 * NN) {
    int dg = base[g + 1] - base[g];
    atomicAdd(&lh[min(dg, 63)], 1);
  }
  __syncthreads();
  if (t < 64 && lh[t]) atomicAdd(&dhist[t], lh[t]);
}

__global__ void dscan64_kernel(int* __restrict__ dhist)
{
  int t = threadIdx.x;   // 64 threads
  int v = dhist[t];
  int x = v;
  #pragma unroll
  for (int off = 1; off < 64; off <<= 1) {
    int y = __shfl_up(x, off, 64);
    if (t >= off) x += y;
  }
  dhist[t] = x - v;      // exclusive base; becomes cursor for dperm
}

__global__ __launch_bounds__(256) void dperm_kernel(
    const int* __restrict__ base, int* __restrict__ dhist, int* __restrict__ perm)
{
  __shared__ int lh[64];
  __shared__ int lb[64];
  int t = threadIdx.x;
  if (t < 64) lh[t] = 0;
  __syncthreads();
  int g = blockIdx.x * 256 + t;
  int b = 0, r = 0;
  bool v = (g < 2 * NN);
  if (v) {
    int dg = base[g + 1] - base[g];
    b = min(dg, 63);
    r = atomicAdd(&lh[b], 1);
  }
  __syncthreads();
  if (t < 64 && lh[t]) lb[t] = atomicAdd(&dhist[t], lh[t]);
  __syncthreads();
  if (v) perm[lb[b] + r] = g;
}

// ---------------------------------------------------------------------------
// Gather: 8-lane subgroup per degree-sorted (node,dir) group, packed-f32 math.
// ---------------------------------------------------------------------------
template<bool FIRST, bool WITH_AU>
__global__ __launch_bounds__(256) void gather_kernel(
    const float* __restrict__ h, const unsigned short* __restrict__ hb,
    const float4* __restrict__ pay, const int* __restrict__ base,
    const int* __restrict__ perm,
    const float* __restrict__ to_w1, const float* __restrict__ to_b1,
    const float* __restrict__ to_w2, const float* __restrict__ to_b2,
    const float* __restrict__ fr_w1, const float* __restrict__ fr_b1,
    const float* __restrict__ fr_w2, const float* __restrict__ fr_b2,
    float* __restrict__ mto, float* __restrict__ mfr, int gblocks,
    const float2* __restrict__ pay_au, const float* __restrict__ u,
    const float* __restrict__ y, float w, float* __restrict__ loss)
{
  if (WITH_AU && (int)blockIdx.x >= gblocks) {
    // ---- au_loss body ----
    __shared__ float ss[4];
    int n = (blockIdx.x - gblocks) * 256 + threadIdx.x;
    float acc = 0.0f;
    if (n < NN) {
      float au = 0.0f;
      int beg = base[NN + n] - NE, end = base[NN + n + 1] - NE;
      for (int i = beg; i < end; ++i) {
        float2 q = pay_au[i];
        au = fmaf(q.y, u[__float_as_int(q.x)], au);
      }
      float dlt = au - y[n];
      acc = dlt * dlt;
    }
    #pragma unroll
    for (int off = 32; off > 0; off >>= 1) acc += __shfl_down(acc, off);
    int lane = threadIdx.x & 63, wid = threadIdx.x >> 6;
    if (lane == 0) ss[wid] = acc;
    __syncthreads();
    if (threadIdx.x == 0) atomicAdd(loss, (ss[0] + ss[1] + ss[2] + ss[3]) * w);
    return;
  }

  // ---- gather body ----
  __shared__ __align__(16) float sw[1696];   // per half (848): w1[560] b1@560 w2@576 b2@832
  __shared__ __align__(16) float p1buf[512];
  int t = threadIdx.x;
  for (int i = t; i < 560; i += 256) { sw[i] = to_w1[i]; sw[848 + i] = fr_w1[i]; }
  { int i = t;
    if (i < 256) { sw[576 + i] = to_w2[i]; sw[848 + 576 + i] = fr_w2[i]; }
    if (i < 16) {
      sw[560 + i] = to_b1[i];
      sw[832 + i] = to_b2[i];
      sw[848 + 560 + i] = fr_b1[i];
      sw[848 + 832 + i] = fr_b2[i];
    }
  }
  __syncthreads();

  int sub = (blockIdx.x * 256 + t) >> 3;   // subgroup index (exact: 2N*8 threads)
  int l = t & 7;
  int g = perm[sub];                       // degree-sorted group
  int dir = (g >= NN) ? 1 : 0;             // 0 = mess_to, 1 = mess_from
  int n = g - (dir ? NN : 0);

  const float* w1 = sw + (dir ? 848 : 0);
  const f32x2* w1p = (const f32x2*)w1;     // pairs; row r pair m = w1p[r*8+m]
  const float* b1 = w1 + 560;
  const f32x2* w2p = (const f32x2*)(w1 + 576);
  const f32x2* b2p = (const f32x2*)(w1 + 832);

  f32x2 p1v[8];
  if (FIRST) {
    #pragma unroll
    for (int m = 0; m < 8; ++m) { p1v[m].x = b1[2 * m]; p1v[m].y = b1[2 * m + 1]; }
  } else {
    // cooperative p1: lane l computes outputs 2l,2l+1 (16 pk_fma), exchange via LDS
    float hv[DD];
    load16(h + (size_t)n * DD, hv);
    f32x2 pp; pp.x = b1[2 * l]; pp.y = b1[2 * l + 1];
    #pragma unroll
    for (int k = 0; k < DD; ++k) pk_fma(pp, hv[k], w1p[k * 8 + l]);
    ((f32x2*)p1buf)[t] = pp;
    __syncthreads();
    const f32x2* pb2 = (const f32x2*)&p1buf[(t & ~7) * 2];
    #pragma unroll
    for (int m = 0; m < 8; ++m) p1v[m] = pb2[m];
  }

  f32x2 hs2[8];
  #pragma unroll
  for (int m = 0; m < 8; ++m) hs2[m] = (f32x2)(0.0f);
  int cnt = 0;

  int beg = base[g], end = base[g + 1];
  for (int i = beg + l; i < end; i += 8) {
    float4 q = pay[i];
    int nb = __float_as_int(q.x);
    if (nb >= 0) {
      f32x2 hid[8];
      #pragma unroll
      for (int m = 0; m < 8; ++m) {
        hid[m] = p1v[m];
        pk_fma(hid[m], q.y, w1p[256 + m]);   // row 32
        pk_fma(hid[m], q.z, w1p[264 + m]);   // row 33
        pk_fma(hid[m], q.w, w1p[272 + m]);   // row 34
      }
      if (!FIRST) {
        uint4 qa = *(const uint4*)(hb + (size_t)nb * DD);
        uint4 qb = *(const uint4*)(hb + (size_t)nb * DD + 8);
        float hv[DD];
        hv[0]  = __uint_as_float(qa.x << 16); hv[1]  = __uint_as_float(qa.x & 0xFFFF0000u);
        hv[2]  = __uint_as_float(qa.y << 16); hv[3]  = __uint_as_float(qa.y & 0xFFFF0000u);
        hv[4]  = __uint_as_float(qa.z << 16); hv[5]  = __uint_as_float(qa.z & 0xFFFF0000u);
        hv[6]  = __uint_as_float(qa.w << 16); hv[7]  = __uint_as_float(qa.w & 0xFFFF0000u);
        hv[8]  = __uint_as_float(qb.x << 16); hv[9]  = __uint_as_float(qb.x & 0xFFFF0000u);
        hv[10] = __uint_as_float(qb.y << 16); hv[11] = __uint_as_float(qb.y & 0xFFFF0000u);
        hv[12] = __uint_as_float(qb.z << 16); hv[13] = __uint_as_float(qb.z & 0xFFFF0000u);
        hv[14] = __uint_as_float(qb.w << 16); hv[15] = __uint_as_float(qb.w & 0xFFFF0000u);
        #pragma unroll
        for (int k = 0; k < DD; ++k) {
          float x = hv[k];
          #pragma unroll
          for (int m = 0; m < 8; ++m) pk_fma(hid[m], x, w1p[(DD + k) * 8 + m]);
        }
      }
      #pragma unroll
      for (int m = 0; m < 8; ++m) {
        f32x2 r;
        r.x = fmaxf(hid[m].x, 0.0f);
        r.y = fmaxf(hid[m].y, 0.0f);
        pk_add(hs2[m], r);
      }
      ++cnt;
    }
  }

  // reduce across the 8-lane subgroup
  #pragma unroll
  for (int m = 0; m < 8; ++m) {
    hs2[m].x += __shfl_xor(hs2[m].x, 1, 64);
    hs2[m].y += __shfl_xor(hs2[m].y, 1, 64);
    hs2[m].x += __shfl_xor(hs2[m].x, 2, 64);
    hs2[m].y += __shfl_xor(hs2[m].y, 2, 64);
    hs2[m].x += __shfl_xor(hs2[m].x, 4, 64);
    hs2[m].y += __shfl_xor(hs2[m].y, 4, 64);
  }
  cnt += __shfl_xor(cnt, 1, 64);
  cnt += __shfl_xor(cnt, 2, 64);
  cnt += __shfl_xor(cnt, 4, 64);

  // layer 2 once per group, feature-split: lane l emits outputs [2l, 2l+2)
  float c = (float)cnt;
  f32x2 macc;
  macc.x = c * b2p[l].x;
  macc.y = c * b2p[l].y;
  #pragma unroll
  for (int k = 0; k < DD; ++k) {
    float x = (k & 1) ? hs2[k >> 1].y : hs2[k >> 1].x;
    pk_fma(macc, x, w2p[k * 8 + l]);
  }
  float* dst = (dir ? mfr : mto) + (size_t)n * DD + 2 * l;
  *(float2*)dst = make_float2(macc.x, macc.y);
}

// ---------------------------------------------------------------------------
// Node kernel (packed-f32): h += ALPHA*psi([h,mto,mfr,prb]); u = dec(h); hb=bf16(h)
// FIRST=true: h == 0 -> skip h load and its 16 rows.
// ---------------------------------------------------------------------------
template<bool FIRST>
__global__ __launch_bounds__(256) void node_kernel(
    float* __restrict__ h, unsigned short* __restrict__ hb,
    const float* __restrict__ mto, const float* __restrict__ mfr,
    const float* __restrict__ prb,
    const float* __restrict__ psi_w1, const float* __restrict__ psi_b1,
    const float* __restrict__ psi_w2, const float* __restrict__ psi_b2,
    const float* __restrict__ dec_w1, const float* __restrict__ dec_b1,
    const float* __restrict__ dec_w2, const float* __restrict__ dec_b2,
    float* __restrict__ u)
{
  __shared__ __align__(16) float sw[1362];
  for (int i = threadIdx.x; i < 784; i += 256) sw[i] = psi_w1[i];
  { int i = threadIdx.x;
    if (i < 256) { sw[800 + i] = psi_w2[i]; sw[1072 + i] = dec_w1[i]; }
    if (i < 16) {
      sw[784 + i] = psi_b1[i];
      sw[1056 + i] = psi_b2[i];
      sw[1328 + i] = dec_b1[i];
      sw[1344 + i] = dec_w2[i];
    }
    if (i == 0) sw[1360] = dec_b2[0];
  }
  __syncthreads();

  int n = blockIdx.x * 256 + threadIdx.x;
  if (n >= NN) return;

  const f32x2* swp = (const f32x2*)sw;

  float hv[DD], mt[DD], mf[DD];
  if (!FIRST) {
    load16(h + (size_t)n * DD, hv);
  } else {
    for (int j = 0; j < DD; ++j) hv[j] = 0.0f;
  }
  load16(mto + (size_t)n * DD, mt);
  load16(mfr + (size_t)n * DD, mf);
  float p = prb[n];

  f32x2 hid[8];
  #pragma unroll
  for (int m = 0; m < 8; ++m) { hid[m].x = sw[784 + 2 * m]; hid[m].y = sw[784 + 2 * m + 1]; }
  if (!FIRST) {
    #pragma unroll
    for (int i = 0; i < DD; ++i) {
      float x = hv[i];
      #pragma unroll
      for (int m = 0; m < 8; ++m) pk_fma(hid[m], x, swp[i * 8 + m]);
    }
  }
  #pragma unroll
  for (int i = 0; i < DD; ++i) {
    float x = mt[i];
    #pragma unroll
    for (int m = 0; m < 8; ++m) pk_fma(hid[m], x, swp[(DD + i) * 8 + m]);
  }
  #pragma unroll
  for (int i = 0; i < DD; ++i) {
    float x = mf[i];
    #pragma unroll
    for (int m = 0; m < 8; ++m) pk_fma(hid[m], x, swp[(2 * DD + i) * 8 + m]);
  }
  #pragma unroll
  for (int m = 0; m < 8; ++m) pk_fma(hid[m], p, swp[48 * 8 + m]);

  float hidf[DD];
  #pragma unroll
  for (int m = 0; m < 8; ++m) {
    hidf[2 * m]     = fmaxf(hid[m].x, 0.0f);
    hidf[2 * m + 1] = fmaxf(hid[m].y, 0.0f);
  }

  f32x2 hn2[8];
  #pragma unroll
  for (int m = 0; m < 8; ++m) { hn2[m].x = sw[1056 + 2 * m]; hn2[m].y = sw[1056 + 2 * m + 1]; }
  #pragma unroll
  for (int i = 0; i < DD; ++i) {
    float x = hidf[i];
    #pragma unroll
    for (int m = 0; m < 8; ++m) pk_fma(hn2[m], x, swp[400 + i * 8 + m]);   // psi_w2 @800
  }
  float hnew[DD];
  #pragma unroll
  for (int m = 0; m < 8; ++m) {
    hnew[2 * m]     = fmaf(ALPHA, hn2[m].x, hv[2 * m]);
    hnew[2 * m + 1] = fmaf(ALPHA, hn2[m].y, hv[2 * m + 1]);
  }
  store16(h + (size_t)n * DD, hnew);

  uint4 pa, pb;
  pa.x = f2bf(hnew[0])  | (f2bf(hnew[1])  << 16);
  pa.y = f2bf(hnew[2])  | (f2bf(hnew[3])  << 16);
  pa.z = f2bf(hnew[4])  | (f2bf(hnew[5])  << 16);
  pa.w = f2bf(hnew[6])  | (f2bf(hnew[7])  << 16);
  pb.x = f2bf(hnew[8])  | (f2bf(hnew[9])  << 16);
  pb.y = f2bf(hnew[10]) | (f2bf(hnew[11]) << 16);
  pb.z = f2bf(hnew[12]) | (f2bf(hnew[13]) << 16);
  pb.w = f2bf(hnew[14]) | (f2bf(hnew[15]) << 16);
  *(uint4*)(hb + (size_t)n * DD)     = pa;
  *(uint4*)(hb + (size_t)n * DD + 8) = pb;

  f32x2 h2[8];
  #pragma unroll
  for (int m = 0; m < 8; ++m) { h2[m].x = sw[1328 + 2 * m]; h2[m].y = sw[1328 + 2 * m + 1]; }
  #pragma unroll
  for (int i = 0; i < DD; ++i) {
    float x = hnew[i];
    #pragma unroll
    for (int m = 0; m < 8; ++m) pk_fma(h2[m], x, swp[536 + i * 8 + m]);    // dec_w1 @1072
  }
  float uo = sw[1360];
  #pragma unroll
  for (int m = 0; m < 8; ++m) {
    uo += fmaxf(h2[m].x, 0.0f) * sw[1344 + 2 * m];
    uo += fmaxf(h2[m].y, 0.0f) * sw[1344 + 2 * m + 1];
  }
  u[n] = uo;
}

extern "C" void kernel_launch(void* const* d_in, const int* in_sizes, int n_in,
                              void* d_out, int out_size, void* d_ws, size_t ws_size,
                              hipStream_t stream) {
  const int*   ei        = (const int*)d_in[0];
  const float* ea        = (const float*)d_in[1];
  const float* a_ij      = (const float*)d_in[2];
  const float* prb       = (const float*)d_in[3];
  const float* y         = (const float*)d_in[5];
  const float* phi_to_w1 = (const float*)d_in[6];
  const float* phi_to_b1 = (const float*)d_in[7];
  const float* phi_to_w2 = (const float*)d_in[8];
  const float* phi_to_b2 = (const float*)d_in[9];
  const float* phi_fr_w1 = (const float*)d_in[10];
  const float* phi_fr_b1 = (const float*)d_in[11];
  const float* phi_fr_w2 = (const float*)d_in[12];
  const float* phi_fr_b2 = (const float*)d_in[13];
  const float* psi_w1    = (const float*)d_in[14];
  const float* psi_b1    = (const float*)d_in[15];
  const float* psi_w2    = (const float*)d_in[16];
  const float* psi_b2    = (const float*)d_in[17];
  const float* dec_w1    = (const float*)d_in[18];
  const float* dec_b1    = (const float*)d_in[19];
  const float* dec_w2    = (const float*)d_in[20];
  const float* dec_b2    = (const float*)d_in[21];

  float* out_u    = (float*)d_out;
  float* out_loss = out_u + NN;

  char* wp = (char*)d_ws;
  auto carve = [&](size_t bytes) { void* p = (void*)wp; wp += (bytes + 15) & ~(size_t)15; return p; };
  float4* pay      = (float4*)carve((size_t)2 * NE * 16);   // [dst-sorted | src-sorted]
  float2* pay_au   = (float2*)carve((size_t)NE * 8);
  float*  h        = (float*)carve((size_t)NN * DD * 4);
  unsigned short* hb16 = (unsigned short*)carve((size_t)NN * DD * 2);
  float*  mto      = (float*)carve((size_t)NN * DD * 4);
  float*  mfr      = (float*)carve((size_t)NN * DD * 4);
  int*    rank_dst = (int*)carve((size_t)NE * 4);
  int*    rank_src = (int*)carve((size_t)NE * 4);
  int*    base     = (int*)carve((size_t)(2 * NN + 1) * 4);
  int*    hist     = (int*)carve((size_t)2 * NN * 4);
  int*    dhist    = (int*)carve(64 * 4);                   // contiguous after hist
  int*    sums     = (int*)carve(256 * 4);
  int*    perm     = rank_dst;   // alias: rank_dst dead after scatter

  hipMemsetAsync(out_loss, 0, 4, stream);
  hipMemsetAsync(hist, 0, ((size_t)2 * NN + 64) * 4, stream);  // hist + dhist

  const int EB  = (NE + 255) / 256;             // 3125
  const int NB  = (NN + 255) / 256;             // 391
  const int L2N = 2 * NN;                       // 200000
  const int SB1 = (L2N + 1023) / 1024;          // 196
  const int SB3 = (L2N + 255) / 256;            // 782
  const int DB  = (L2N + 255) / 256;            // 782
  const int GB8 = (L2N * 8) / 256;              // 6250 (exact)

  hist_kernel<<<EB, 256, 0, stream>>>(ei, hist, rank_dst, rank_src);
  scan1_kernel<<<SB1, 256, 0, stream>>>(hist, base, sums, L2N);
  scan2_kernel<<<1, 256, 0, stream>>>(sums, SB1, base + L2N);
  scan3_kernel<<<SB3, 256, 0, stream>>>(base, sums, L2N);
  scatter_kernel<<<EB, 256, 0, stream>>>(ei, ea, a_ij, base, rank_dst, rank_src,
                                         pay, pay_au);
  dbucket_kernel<<<DB, 256, 0, stream>>>(base, dhist);
  dscan64_kernel<<<1, 64, 0, stream>>>(dhist);
  dperm_kernel<<<DB, 256, 0, stream>>>(base, dhist, perm);

  const float gw[3] = {0.81f, 0.9f, 1.0f};  // gamma^(K-1-t)

  // t = 0 (h == 0)
  gather_kernel<true, false><<<GB8, 256, 0, stream>>>(
      h, hb16, pay, base, perm,
      phi_to_w1, phi_to_b1, phi_to_w2, phi_to_b2,
      phi_fr_w1, phi_fr_b1, phi_fr_w2, phi_fr_b2,
      mto, mfr, GB8, pay_au, out_u, y, 0.0f, out_loss);
  node_kernel<true><<<NB, 256, 0, stream>>>(
      h, hb16, mto, mfr, prb,
      psi_w1, psi_b1, psi_w2, psi_b2,
      dec_w1, dec_b1, dec_w2, dec_b2, out_u);

  // t = 1, 2: gather(t) fused with au_loss(t-1)
  for (int t = 1; t < 3; ++t) {
    gather_kernel<false, true><<<GB8 + NB, 256, 0, stream>>>(
        h, hb16, pay, base, perm,
        phi_to_w1 + t * 560, phi_to_b1 + t * 16, phi_to_w2 + t * 256, phi_to_b2 + t * 16,
        phi_fr_w1 + t * 560, phi_fr_b1 + t * 16, phi_fr_w2 + t * 256, phi_fr_b2 + t * 16,
        mto, mfr, GB8, pay_au, out_u, y, gw[t - 1] / (float)NN, out_loss);
    node_kernel<false><<<NB, 256, 0, stream>>>(
        h, hb16, mto, mfr, prb,
        psi_w1 + t * 784, psi_b1 + t * 16, psi_w2 + t * 256, psi_b2 + t * 16,
        dec_w1 + t * 256, dec_b1 + t * 16, dec_w2 + t * 16, dec_b2 + t, out_u);
  }

  // final residual loss (t = 2's u)
  gather_kernel<false, true><<<NB, 256, 0, stream>>>(
      h, hb16, pay, base, perm,
      phi_to_w1, phi_to_b1, phi_to_w2, phi_to_b2,
      phi_fr_w1, phi_fr_b1, phi_fr_w2, phi_fr_b2,
      mto, mfr, 0, pay_au, out_u, y, gw[2] / (float)NN, out_loss);
}

// Round 11
// 318.298 us; speedup vs baseline: 1.1560x; 1.1560x over previous
//
#include <hip/hip_runtime.h>

#define NN 100000
#define NE 800000
#define DD 16
#define ALPHA 0.1f

typedef _Float16 h2_t __attribute__((ext_vector_type(2)));
union U32H2 { unsigned u; h2_t h; };

__device__ __forceinline__ unsigned pack2h(float a, float b) {
  U32H2 v; v.h[0] = (_Float16)a; v.h[1] = (_Float16)b; return v.u;
}

// f32 += f16x2 . f16x2  (mixed-precision dot2); exact-math fallback if absent
__device__ __forceinline__ float dot2(unsigned a, unsigned b, float c) {
  U32H2 ua, ub; ua.u = a; ub.u = b;
#if __has_builtin(__builtin_amdgcn_fdot2)
  return __builtin_amdgcn_fdot2(ua.h, ub.h, c, false);
#else
  return fmaf((float)ua.h[0], (float)ub.h[0],
         fmaf((float)ua.h[1], (float)ub.h[1], c));
#endif
}

__device__ __forceinline__ void load16(const float* __restrict__ p, float* r) {
  float4 v0 = *(const float4*)(p + 0);
  float4 v1 = *(const float4*)(p + 4);
  float4 v2 = *(const float4*)(p + 8);
  float4 v3 = *(const float4*)(p + 12);
  r[0]=v0.x; r[1]=v0.y; r[2]=v0.z; r[3]=v0.w;
  r[4]=v1.x; r[5]=v1.y; r[6]=v1.z; r[7]=v1.w;
  r[8]=v2.x; r[9]=v2.y; r[10]=v2.z; r[11]=v2.w;
  r[12]=v3.x; r[13]=v3.y; r[14]=v3.z; r[15]=v3.w;
}

__device__ __forceinline__ void store16(float* __restrict__ p, const float* r) {
  *(float4*)(p + 0)  = make_float4(r[0], r[1], r[2], r[3]);
  *(float4*)(p + 4)  = make_float4(r[4], r[5], r[6], r[7]);
  *(float4*)(p + 8)  = make_float4(r[8], r[9], r[10], r[11]);
  *(float4*)(p + 12) = make_float4(r[12], r[13], r[14], r[15]);
}

// ---------------------------------------------------------------------------
// hist + rank over unified [in | out] histogram of length 2N
// ---------------------------------------------------------------------------
__global__ __launch_bounds__(256) void hist_kernel(
    const int* __restrict__ ei, int* __restrict__ hist,
    int* __restrict__ rank_dst, int* __restrict__ rank_src)
{
  int e = blockIdx.x * 256 + threadIdx.x;
  if (e >= NE) return;
  int s = ei[e];
  int d = ei[NE + e];
  rank_dst[e] = atomicAdd(&hist[d], 1);
  rank_src[e] = atomicAdd(&hist[NN + s], 1);
}

// scan1 + fused degree-bucket histogram (reads each degree anyway)
__global__ __launch_bounds__(256) void scan1_kernel(
    const int* __restrict__ in, int* __restrict__ out, int* __restrict__ sums,
    int L, int* __restrict__ dhist)
{
  __shared__ int sh[256];
  __shared__ int lh[64];
  int t = threadIdx.x;
  if (t < 64) lh[t] = 0;
  int i0 = blockIdx.x * 1024 + t * 4;
  int v0 = (i0 + 0 < L) ? in[i0 + 0] : 0;
  int v1 = (i0 + 1 < L) ? in[i0 + 1] : 0;
  int v2 = (i0 + 2 < L) ? in[i0 + 2] : 0;
  int v3 = (i0 + 3 < L) ? in[i0 + 3] : 0;
  int tot = v0 + v1 + v2 + v3;
  sh[t] = tot;
  __syncthreads();
  if (i0 + 0 < L) atomicAdd(&lh[min(v0, 63)], 1);
  if (i0 + 1 < L) atomicAdd(&lh[min(v1, 63)], 1);
  if (i0 + 2 < L) atomicAdd(&lh[min(v2, 63)], 1);
  if (i0 + 3 < L) atomicAdd(&lh[min(v3, 63)], 1);
  int val = tot;
  for (int off = 1; off < 256; off <<= 1) {
    int x = (t >= off) ? sh[t - off] : 0;
    __syncthreads();
    val += x; sh[t] = val;
    __syncthreads();
  }
  if (t == 255) sums[blockIdx.x] = val;
  int run = val - tot;
  if (i0 + 0 < L) out[i0 + 0] = run; run += v0;
  if (i0 + 1 < L) out[i0 + 1] = run; run += v1;
  if (i0 + 2 < L) out[i0 + 2] = run; run += v2;
  if (i0 + 3 < L) out[i0 + 3] = run;
  if (t < 64 && lh[t]) atomicAdd(&dhist[t], lh[t]);
}

// scan2 + fused 64-bin exclusive scan of dhist (wave 0)
__global__ __launch_bounds__(256) void scan2_kernel(
    int* __restrict__ sums, int nb, int* __restrict__ out_total,
    int* __restrict__ dhist)
{
  __shared__ int sh[256];
  int t = threadIdx.x;
  int v = (t < nb) ? sums[t] : 0;
  sh[t] = v;
  __syncthreads();
  int val = v;
  for (int off = 1; off < 256; off <<= 1) {
    int x = (t >= off) ? sh[t - off] : 0;
    __syncthreads();
    val += x; sh[t] = val;
    __syncthreads();
  }
  if (t < nb) sums[t] = val - v;
  if (t == 255) *out_total = val;   // sentinel = 2*NE at base[2N]
  if (t < 64) {                     // wave 0: scan degree bins
    int dv = dhist[t];
    int dx = dv;
    #pragma unroll
    for (int off = 1; off < 64; off <<= 1) {
      int dy = __shfl_up(dx, off, 64);
      if (t >= off) dx += dy;
    }
    dhist[t] = dx - dv;             // exclusive base -> cursor for dperm
  }
}

__global__ __launch_bounds__(256) void scan3_kernel(
    int* __restrict__ out, const int* __restrict__ sums, int L)
{
  int i = blockIdx.x * 256 + threadIdx.x;
  if (i < L) out[i] += sums[i >> 10];
}

// atomic-free payload scatter into unified pay[2*NE]
__global__ __launch_bounds__(256) void scatter_kernel(
    const int* __restrict__ ei, const float* __restrict__ ea, const float* __restrict__ a,
    const int* __restrict__ base,
    const int* __restrict__ rank_dst, const int* __restrict__ rank_src,
    float4* __restrict__ pay, float2* __restrict__ pay_au)
{
  int e = blockIdx.x * 256 + threadIdx.x;
  if (e >= NE) return;
  int s = ei[e];
  int d = ei[NE + e];
  float e0 = ea[3 * (size_t)e], e1 = ea[3 * (size_t)e + 1], e2 = ea[3 * (size_t)e + 2];
  int sl = (s == d);
  int pd = base[d] + rank_dst[e];
  pay[pd] = make_float4(__int_as_float(sl ? -1 : s), e0, e1, e2);
  int ps = base[NN + s] + rank_src[e];
  pay[ps] = make_float4(__int_as_float(sl ? -1 : d), e0, e1, e2);
  pay_au[ps - NE] = make_float2(__int_as_float(d), a[e]);
}

// degree-sorted permutation (after scatter: perm aliases rank_dst)
__global__ __launch_bounds__(256) void dperm_kernel(
    const int* __restrict__ base, int* __restrict__ dhist, int* __restrict__ perm)
{
  __shared__ int lh[64];
  __shared__ int lb[64];
  int t = threadIdx.x;
  if (t < 64) lh[t] = 0;
  __syncthreads();
  int g = blockIdx.x * 256 + t;
  int b = 0, r = 0;
  bool v = (g < 2 * NN);
  if (v) {
    int dg = base[g + 1] - base[g];
    b = min(dg, 63);
    r = atomicAdd(&lh[b], 1);
  }
  __syncthreads();
  if (t < 64 && lh[t]) lb[t] = atomicAdd(&dhist[t], lh[t]);
  __syncthreads();
  if (v) perm[lb[b] + r] = g;
}

// ---------------------------------------------------------------------------
// Gather: 8-lane subgroup per degree-sorted (node,dir) group.
// Neighbor + attr(32/33) matmul via f16 dot2 (weights pre-paired in LDS).
// ---------------------------------------------------------------------------
template<bool FIRST, bool WITH_AU>
__global__ __launch_bounds__(256) void gather_kernel(
    const float* __restrict__ h, const unsigned* __restrict__ hb,
    const float4* __restrict__ pay, const int* __restrict__ base,
    const int* __restrict__ perm,
    const float* __restrict__ to_w1, const float* __restrict__ to_b1,
    const float* __restrict__ to_w2, const float* __restrict__ to_b2,
    const float* __restrict__ fr_w1, const float* __restrict__ fr_b1,
    const float* __restrict__ fr_w2, const float* __restrict__ fr_b2,
    float* __restrict__ mto, float* __restrict__ mfr, int gblocks,
    const float2* __restrict__ pay_au, const float* __restrict__ u,
    const float* __restrict__ y, float w, float* __restrict__ loss)
{
  if (WITH_AU && (int)blockIdx.x >= gblocks) {
    // ---- au_loss body ----
    __shared__ float ss[4];
    int n = (blockIdx.x - gblocks) * 256 + threadIdx.x;
    float acc = 0.0f;
    if (n < NN) {
      float au = 0.0f;
      int beg = base[NN + n] - NE, end = base[NN + n + 1] - NE;
      for (int i = beg; i < end; ++i) {
        float2 q = pay_au[i];
        au = fmaf(q.y, u[__float_as_int(q.x)], au);
      }
      float dlt = au - y[n];
      acc = dlt * dlt;
    }
    #pragma unroll
    for (int off = 32; off > 0; off >>= 1) acc += __shfl_down(acc, off);
    int lane = threadIdx.x & 63, wid = threadIdx.x >> 6;
    if (lane == 0) ss[wid] = acc;
    __syncthreads();
    if (threadIdx.x == 0) atomicAdd(loss, (ss[0] + ss[1] + ss[2] + ss[3]) * w);
    return;
  }

  // ---- gather body ----
  __shared__ float sw[1696];       // per half (848): w1[560] b1@560 w2@576 b2@832
  __shared__ unsigned w1h[2][144]; // f16 pairs: kp<8 rows {16+2kp,17+2kp}; kp=8 rows {32,33}
  __shared__ float p1buf[512];
  int t = threadIdx.x;
  for (int i = t; i < 560; i += 256) { sw[i] = to_w1[i]; sw[848 + i] = fr_w1[i]; }
  { int i = t;
    if (i < 256) { sw[576 + i] = to_w2[i]; sw[848 + 576 + i] = fr_w2[i]; }
    if (i < 16) {
      sw[560 + i] = to_b1[i];
      sw[832 + i] = to_b2[i];
      sw[848 + 560 + i] = fr_b1[i];
      sw[848 + 832 + i] = fr_b2[i];
    }
  }
  for (int i = t; i < 288; i += 256) {
    int dr = i / 144, idx = i % 144;
    int kp = idx >> 4, j = idx & 15;
    int r0 = (kp < 8) ? (16 + 2 * kp) : 32;
    const float* W = dr ? fr_w1 : to_w1;
    w1h[dr][idx] = pack2h(W[r0 * DD + j], W[(r0 + 1) * DD + j]);
  }
  __syncthreads();

  int sub = (blockIdx.x * 256 + t) >> 3;   // subgroup index (exact: 2N*8 threads)
  int l = t & 7;
  int g = perm[sub];                       // degree-sorted group
  int dir = (g >= NN) ? 1 : 0;             // 0 = mess_to, 1 = mess_from
  int n = g - (dir ? NN : 0);

  const float* w1 = sw + (dir ? 848 : 0);
  const float* b1 = w1 + 560;
  const float* w2 = w1 + 576;
  const float* b2 = w1 + 832;
  const unsigned* whn = w1h[dir];          // neighbor pairs [kp*16+j]
  const unsigned* wha = w1h[dir] + 128;    // attr rows 32,33 pairs [j]

  float p1v[DD];
  if (FIRST) {
    #pragma unroll
    for (int j = 0; j < DD; ++j) p1v[j] = b1[j];
  } else {
    // cooperative p1: lane l computes outputs 2l,2l+1 (32 FMA), exchange via LDS
    float hv[DD];
    load16(h + (size_t)n * DD, hv);
    int j0 = 2 * l;
    float pa = b1[j0], pb = b1[j0 + 1];
    #pragma unroll
    for (int k = 0; k < DD; ++k) {
      pa = fmaf(hv[k], w1[k * DD + j0], pa);
      pb = fmaf(hv[k], w1[k * DD + j0 + 1], pb);
    }
    p1buf[2 * t] = pa;
    p1buf[2 * t + 1] = pb;
    __syncthreads();
    const float* pbase = &p1buf[(t & ~7) * 2];
    #pragma unroll
    for (int j = 0; j < DD; ++j) p1v[j] = pbase[j];
  }

  float hs_[DD];
  #pragma unroll
  for (int j = 0; j < DD; ++j) hs_[j] = 0.0f;
  int cnt = 0;

  int beg = base[g], end = base[g + 1];
  for (int i = beg + l; i < end; i += 8) {
    float4 q = pay[i];
    int nb = __float_as_int(q.x);
    if (nb >= 0) {
      unsigned e01 = pack2h(q.y, q.z);
      float hid[DD];
      #pragma unroll
      for (int j = 0; j < DD; ++j)
        hid[j] = fmaf(q.w, w1[34 * DD + j], dot2(e01, wha[j], p1v[j]));
      if (!FIRST) {
        uint4 qa = *(const uint4*)(hb + (size_t)nb * 8);
        uint4 qb = *(const uint4*)(hb + (size_t)nb * 8 + 4);
        unsigned hp[8] = {qa.x, qa.y, qa.z, qa.w, qb.x, qb.y, qb.z, qb.w};
        #pragma unroll
        for (int kp = 0; kp < 8; ++kp) {
          unsigned hv2 = hp[kp];
          #pragma unroll
          for (int j = 0; j < DD; ++j) hid[j] = dot2(hv2, whn[kp * 16 + j], hid[j]);
        }
      }
      #pragma unroll
      for (int j = 0; j < DD; ++j) hs_[j] += fmaxf(hid[j], 0.0f);
      ++cnt;
    }
  }

  // reduce across the 8-lane subgroup
  #pragma unroll
  for (int j = 0; j < DD; ++j) {
    hs_[j] += __shfl_xor(hs_[j], 1, 64);
    hs_[j] += __shfl_xor(hs_[j], 2, 64);
    hs_[j] += __shfl_xor(hs_[j], 4, 64);
  }
  cnt += __shfl_xor(cnt, 1, 64);
  cnt += __shfl_xor(cnt, 2, 64);
  cnt += __shfl_xor(cnt, 4, 64);

  // layer 2 once per group, feature-split: lane l emits outputs [2l, 2l+2)
  float c = (float)cnt;
  float m0 = c * b2[2 * l + 0];
  float m1 = c * b2[2 * l + 1];
  #pragma unroll
  for (int k = 0; k < DD; ++k) {
    float x = hs_[k];
    m0 = fmaf(x, w2[k * DD + 2 * l + 0], m0);
    m1 = fmaf(x, w2[k * DD + 2 * l + 1], m1);
  }
  float* dst = (dir ? mfr : mto) + (size_t)n * DD + 2 * l;
  *(float2*)dst = make_float2(m0, m1);
}

// ---------------------------------------------------------------------------
// Node kernel: h += ALPHA*psi([h,mto,mfr,prb]); u = dec(h); hb = f16(h)
// FIRST=true: h == 0 -> skip h load and its 16 rows.
// ---------------------------------------------------------------------------
template<bool FIRST>
__global__ __launch_bounds__(256) void node_kernel(
    float* __restrict__ h, unsigned* __restrict__ hb,
    const float* __restrict__ mto, const float* __restrict__ mfr,
    const float* __restrict__ prb,
    const float* __restrict__ psi_w1, const float* __restrict__ psi_b1,
    const float* __restrict__ psi_w2, const float* __restrict__ psi_b2,
    const float* __restrict__ dec_w1, const float* __restrict__ dec_b1,
    const float* __restrict__ dec_w2, const float* __restrict__ dec_b2,
    float* __restrict__ u)
{
  __shared__ float sw[1361];
  for (int i = threadIdx.x; i < 784; i += 256) sw[i] = psi_w1[i];
  { int i = threadIdx.x;
    if (i < 256) { sw[800 + i] = psi_w2[i]; sw[1072 + i] = dec_w1[i]; }
    if (i < 16) {
      sw[784 + i] = psi_b1[i];
      sw[1056 + i] = psi_b2[i];
      sw[1328 + i] = dec_b1[i];
      sw[1344 + i] = dec_w2[i];
    }
    if (i == 0) sw[1360] = dec_b2[0];
  }
  __syncthreads();

  int n = blockIdx.x * 256 + threadIdx.x;
  if (n >= NN) return;

  float hv[DD], mt[DD], mf[DD];
  if (!FIRST) {
    load16(h + (size_t)n * DD, hv);
  } else {
    for (int j = 0; j < DD; ++j) hv[j] = 0.0f;
  }
  load16(mto + (size_t)n * DD, mt);
  load16(mfr + (size_t)n * DD, mf);
  float p = prb[n];

  float hid[DD];
  #pragma unroll
  for (int j = 0; j < DD; ++j) hid[j] = sw[784 + j];
  if (!FIRST) {
    #pragma unroll
    for (int i = 0; i < DD; ++i) {
      float x = hv[i];
      #pragma unroll
      for (int j = 0; j < DD; ++j) hid[j] = fmaf(x, sw[i * DD + j], hid[j]);
    }
  }
  #pragma unroll
  for (int i = 0; i < DD; ++i) {
    float x = mt[i];
    #pragma unroll
    for (int j = 0; j < DD; ++j) hid[j] = fmaf(x, sw[(DD + i) * DD + j], hid[j]);
  }
  #pragma unroll
  for (int i = 0; i < DD; ++i) {
    float x = mf[i];
    #pragma unroll
    for (int j = 0; j < DD; ++j) hid[j] = fmaf(x, sw[(2 * DD + i) * DD + j], hid[j]);
  }
  #pragma unroll
  for (int j = 0; j < DD; ++j) hid[j] = fmaf(p, sw[48 * DD + j], hid[j]);
  #pragma unroll
  for (int j = 0; j < DD; ++j) hid[j] = fmaxf(hid[j], 0.0f);

  float hnew[DD];
  #pragma unroll
  for (int j = 0; j < DD; ++j) hnew[j] = sw[1056 + j];
  #pragma unroll
  for (int i = 0; i < DD; ++i) {
    float x = hid[i];
    #pragma unroll
    for (int j = 0; j < DD; ++j) hnew[j] = fmaf(x, sw[800 + i * DD + j], hnew[j]);
  }
  #pragma unroll
  for (int j = 0; j < DD; ++j) hnew[j] = fmaf(ALPHA, hnew[j], hv[j]);
  store16(h + (size_t)n * DD, hnew);

  uint4 pa, pb;
  pa.x = pack2h(hnew[0],  hnew[1]);
  pa.y = pack2h(hnew[2],  hnew[3]);
  pa.z = pack2h(hnew[4],  hnew[5]);
  pa.w = pack2h(hnew[6],  hnew[7]);
  pb.x = pack2h(hnew[8],  hnew[9]);
  pb.y = pack2h(hnew[10], hnew[11]);
  pb.z = pack2h(hnew[12], hnew[13]);
  pb.w = pack2h(hnew[14], hnew[15]);
  *(uint4*)(hb + (size_t)n * 8)     = pa;
  *(uint4*)(hb + (size_t)n * 8 + 4) = pb;

  float hid2[DD];
  #pragma unroll
  for (int j = 0; j < DD; ++j) hid2[j] = sw[1328 + j];
  #pragma unroll
  for (int i = 0; i < DD; ++i) {
    float x = hnew[i];
    #pragma unroll
    for (int j = 0; j < DD; ++j) hid2[j] = fmaf(x, sw[1072 + i * DD + j], hid2[j]);
  }
  float uo = sw[1360];
  #pragma unroll
  for (int i = 0; i < DD; ++i) uo += fmaxf(hid2[i], 0.0f) * sw[1344 + i];
  u[n] = uo;
}

extern "C" void kernel_launch(void* const* d_in, const int* in_sizes, int n_in,
                              void* d_out, int out_size, void* d_ws, size_t ws_size,
                              hipStream_t stream) {
  const int*   ei        = (const int*)d_in[0];
  const float* ea        = (const float*)d_in[1];
  const float* a_ij      = (const float*)d_in[2];
  const float* prb       = (const float*)d_in[3];
  const float* y         = (const float*)d_in[5];
  const float* phi_to_w1 = (const float*)d_in[6];
  const float* phi_to_b1 = (const float*)d_in[7];
  const float* phi_to_w2 = (const float*)d_in[8];
  const float* phi_to_b2 = (const float*)d_in[9];
  const float* phi_fr_w1 = (const float*)d_in[10];
  const float* phi_fr_b1 = (const float*)d_in[11];
  const float* phi_fr_w2 = (const float*)d_in[12];
  const float* phi_fr_b2 = (const float*)d_in[13];
  const float* psi_w1    = (const float*)d_in[14];
  const float* psi_b1    = (const float*)d_in[15];
  const float* psi_w2    = (const float*)d_in[16];
  const float* psi_b2    = (const float*)d_in[17];
  const float* dec_w1    = (const float*)d_in[18];
  const float* dec_b1    = (const float*)d_in[19];
  const float* dec_w2    = (const float*)d_in[20];
  const float* dec_b2    = (const float*)d_in[21];

  float* out_u    = (float*)d_out;
  float* out_loss = out_u + NN;

  char* wp = (char*)d_ws;
  auto carve = [&](size_t bytes) { void* p = (void*)wp; wp += (bytes + 15) & ~(size_t)15; return p; };
  float4*   pay    = (float4*)carve((size_t)2 * NE * 16);   // [dst-sorted | src-sorted]
  float2*   pay_au = (float2*)carve((size_t)NE * 8);
  float*    h      = (float*)carve((size_t)NN * DD * 4);
  unsigned* hb16   = (unsigned*)carve((size_t)NN * 8 * 4);  // f16x2 pairs, 8 u32/node
  float*    mto    = (float*)carve((size_t)NN * DD * 4);
  float*    mfr    = (float*)carve((size_t)NN * DD * 4);
  int*  rank_dst   = (int*)carve((size_t)NE * 4);
  int*  rank_src   = (int*)carve((size_t)NE * 4);
  int*  base       = (int*)carve((size_t)(2 * NN + 1) * 4);
  int*  hist       = (int*)carve((size_t)2 * NN * 4);
  int*  dhist      = (int*)carve(64 * 4);                   // contiguous after hist
  int*  sums       = (int*)carve(256 * 4);
  int*  perm       = rank_dst;   // alias: rank_dst dead after scatter

  hipMemsetAsync(out_loss, 0, 4, stream);
  hipMemsetAsync(hist, 0, ((size_t)2 * NN + 64) * 4, stream);  // hist + dhist

  const int EB  = (NE + 255) / 256;             // 3125
  const int NB  = (NN + 255) / 256;             // 391
  const int L2N = 2 * NN;                       // 200000
  const int SB1 = (L2N + 1023) / 1024;          // 196
  const int SB3 = (L2N + 255) / 256;            // 782
  const int GB8 = (L2N * 8) / 256;              // 6250 (exact)

  hist_kernel<<<EB, 256, 0, stream>>>(ei, hist, rank_dst, rank_src);
  scan1_kernel<<<SB1, 256, 0, stream>>>(hist, base, sums, L2N, dhist);
  scan2_kernel<<<1, 256, 0, stream>>>(sums, SB1, base + L2N, dhist);
  scan3_kernel<<<SB3, 256, 0, stream>>>(base, sums, L2N);
  scatter_kernel<<<EB, 256, 0, stream>>>(ei, ea, a_ij, base, rank_dst, rank_src,
                                         pay, pay_au);
  dperm_kernel<<<SB3, 256, 0, stream>>>(base, dhist, perm);

  const float gw[3] = {0.81f, 0.9f, 1.0f};  // gamma^(K-1-t)

  // t = 0 (h == 0)
  gather_kernel<true, false><<<GB8, 256, 0, stream>>>(
      h, hb16, pay, base, perm,
      phi_to_w1, phi_to_b1, phi_to_w2, phi_to_b2,
      phi_fr_w1, phi_fr_b1, phi_fr_w2, phi_fr_b2,
      mto, mfr, GB8, pay_au, out_u, y, 0.0f, out_loss);
  node_kernel<true><<<NB, 256, 0, stream>>>(
      h, hb16, mto, mfr, prb,
      psi_w1, psi_b1, psi_w2, psi_b2,
      dec_w1, dec_b1, dec_w2, dec_b2, out_u);

  // t = 1, 2: gather(t) fused with au_loss(t-1)
  for (int t = 1; t < 3; ++t) {
    gather_kernel<false, true><<<GB8 + NB, 256, 0, stream>>>(
        h, hb16, pay, base, perm,
        phi_to_w1 + t * 560, phi_to_b1 + t * 16, phi_to_w2 + t * 256, phi_to_b2 + t * 16,
        phi_fr_w1 + t * 560, phi_fr_b1 + t * 16, phi_fr_w2 + t * 256, phi_fr_b2 + t * 16,
        mto, mfr, GB8, pay_au, out_u, y, gw[t - 1] / (float)NN, out_loss);
    node_kernel<false><<<NB, 256, 0, stream>>>(
        h, hb16, mto, mfr, prb,
        psi_w1 + t * 784, psi_b1 + t * 16, psi_w2 + t * 256, psi_b2 + t * 16,
        dec_w1 + t * 256, dec_b1 + t * 16, dec_w2 + t * 16, dec_b2 + t, out_u);
  }

  // final residual loss (t = 2's u)
  gather_kernel<false, true><<<NB, 256, 0, stream>>>(
      h, hb16, pay, base, perm,
      phi_to_w1, phi_to_b1, phi_to_w2, phi_to_b2,
      phi_fr_w1, phi_fr_b1, phi_fr_w2, phi_fr_b2,
      mto, mfr, 0, pay_au, out_u, y, gw[2] / (float)NN, out_loss);
}